// Round 10
// baseline (132.107 us; speedup 1.0000x reference)
//
#include <hip/hip_runtime.h>
#include <hip/hip_bf16.h>

#define NN 4096
#define CC 128
#define SCALE 0.088388347648318447f   // 128^-0.5
#define LOG2E 1.4426950408889634f

typedef __attribute__((ext_vector_type(8))) short short8v;
typedef __attribute__((ext_vector_type(4))) float f32x4;
typedef __attribute__((ext_vector_type(16))) float f32x16;

#define Z16 {0.f,0.f,0.f,0.f,0.f,0.f,0.f,0.f,0.f,0.f,0.f,0.f,0.f,0.f,0.f,0.f}

__device__ __forceinline__ short f2bf(float f) {
  unsigned u = __float_as_uint(f);
  u = (u + 0x7FFFu + ((u >> 16) & 1u)) >> 16;
  return (short)u;
}
__device__ __forceinline__ float bf2f(short s) {
  return __uint_as_float(((unsigned)(unsigned short)s) << 16);
}
__device__ __forceinline__ unsigned pk2bf(float lo, float hi) {
  unsigned r;
  asm("v_cvt_pk_bf16_f32 %0, %1, %2" : "=v"(r) : "v"(lo), "v"(hi));
  return r;
}
__device__ __forceinline__ f32x4 mfma16(short8v a, short8v b, f32x4 c) {
  return __builtin_amdgcn_mfma_f32_16x16x32_bf16(a, b, c, 0, 0, 0);
}
__device__ __forceinline__ f32x16 mfma32(short8v a, short8v b, f32x16 c) {
  return __builtin_amdgcn_mfma_f32_32x32x16_bf16(a, b, c, 0, 0, 0);
}
__device__ __forceinline__ void gload16(const void* g, void* l) {
  __builtin_amdgcn_global_load_lds(
      (const __attribute__((address_space(1))) unsigned*)g,
      (__attribute__((address_space(3))) unsigned*)l, 16, 0, 0);
}

// ---------------- prep: weight convert + groupnorm partial sums -------------
__global__ __launch_bounds__(256) void prep_k(
    const float* __restrict__ x,
    const float* __restrict__ wq, const float* __restrict__ wk,
    const float* __restrict__ wv, const float* __restrict__ wo,
    const float* __restrict__ bq, short* __restrict__ wT,
    float* __restrict__ bqs, float* __restrict__ macc,
    float* __restrict__ vacc) {
  if (blockIdx.x >= 256) {
    int gid = (blockIdx.x - 256) * 256 + threadIdx.x;   // 4*16384
    int widx = gid >> 14, e = gid & 16383;
    int kk = e >> 7, n = e & 127;
    const float* src = (widx == 0) ? wq : (widx == 1) ? wk
                     : (widx == 2) ? wv : wo;
    float v = src[kk * 128 + n];
    if (widx == 0) v *= SCALE * LOG2E;
    wT[widx * 16384 + n * 128 + kk] = f2bf(v);
    if (gid < 128) bqs[gid] = bq[gid] * SCALE * LOG2E;
    return;
  }
  // GN partial: batch b, rows [rc*128, rc*128+128) -- contiguous 64 KB
  int b = blockIdx.x >> 5, rc = blockIdx.x & 31;
  const float4* xp = reinterpret_cast<const float4*>(
      x + (size_t)b * NN * CC + (size_t)rc * 128 * CC);
  int tid = threadIdx.x;
  float s = 0.f, ss = 0.f;
  #pragma unroll
  for (int j = 0; j < 16; ++j) {               // float4 idx = tid + 256j
    float4 v = xp[tid + 256 * j];              // group = idx&31 = tid&31
    s  += v.x + v.y + v.z + v.w;
    ss += v.x * v.x + v.y * v.y + v.z * v.z + v.w * v.w;
  }
  __shared__ float as_[256], ass_[256];
  as_[tid] = s; ass_[tid] = ss;
  __syncthreads();
  if (tid < 32) {                              // 8 threads per group -> sum
    float ts = 0.f, tss = 0.f;
    #pragma unroll
    for (int j = 0; j < 8; ++j) { ts += as_[tid + 32 * j]; tss += ass_[tid + 32 * j]; }
    atomicAdd(&macc[b * 32 + tid], ts);
    atomicAdd(&vacc[b * 32 + tid], tss);
  }
}

// ---------------- fused GN-apply + Q/K/V projections ------------------------
// V^T written with bits 2<->3 of n swapped (sigma-permutation) so attention's
// PV B-fragment is a single contiguous b128 with no cross-lane fixups.
__global__ __launch_bounds__(256) void fqkv_k(
    const float* __restrict__ x, const float* __restrict__ macc,
    const float* __restrict__ vacc, const float* __restrict__ gsc,
    const float* __restrict__ gbi, const short* __restrict__ wT,
    const float* __restrict__ bqs, const float* __restrict__ bk,
    const float* __restrict__ bv, short* __restrict__ qout,
    short* __restrict__ kout, short* __restrict__ vtout) {
  __shared__ short wlds[128][136];
  int lane = threadIdx.x & 63, wid = threadIdx.x >> 6;
  int row0 = blockIdx.x * 64 + wid * 16;
  int arow = row0 + (lane & 15);
  int q4 = lane >> 4;
  int bidx = arow >> 12;
  short8v a[4];
  #pragma unroll
  for (int dt = 0; dt < 4; ++dt) {
    int c0 = dt * 32 + q4 * 8;
    float4 v0 = *reinterpret_cast<const float4*>(x + (size_t)arow * CC + c0);
    float4 v1 = *reinterpret_cast<const float4*>(x + (size_t)arow * CC + c0 + 4);
    int g0 = bidx * 32 + (c0 >> 2);
    float mu0 = macc[g0] * (1.f / 16384.f);
    float r0 = rsqrtf(vacc[g0] * (1.f / 16384.f) - mu0 * mu0 + 1e-6f);
    float mu1 = macc[g0 + 1] * (1.f / 16384.f);
    float r1 = rsqrtf(vacc[g0 + 1] * (1.f / 16384.f) - mu1 * mu1 + 1e-6f);
    float4 s0 = *reinterpret_cast<const float4*>(gsc + c0);
    float4 s1 = *reinterpret_cast<const float4*>(gsc + c0 + 4);
    float4 b0 = *reinterpret_cast<const float4*>(gbi + c0);
    float4 b1 = *reinterpret_cast<const float4*>(gbi + c0 + 4);
    union { short s[8]; short8v v; } pk;
    pk.s[0] = f2bf((v0.x - mu0) * r0 * s0.x + b0.x);
    pk.s[1] = f2bf((v0.y - mu0) * r0 * s0.y + b0.y);
    pk.s[2] = f2bf((v0.z - mu0) * r0 * s0.z + b0.z);
    pk.s[3] = f2bf((v0.w - mu0) * r0 * s0.w + b0.w);
    pk.s[4] = f2bf((v1.x - mu1) * r1 * s1.x + b1.x);
    pk.s[5] = f2bf((v1.y - mu1) * r1 * s1.y + b1.y);
    pk.s[6] = f2bf((v1.z - mu1) * r1 * s1.z + b1.z);
    pk.s[7] = f2bf((v1.w - mu1) * r1 * s1.w + b1.w);
    a[dt] = pk.v;
  }
  for (int ph = 0; ph < 3; ++ph) {
    if (ph) __syncthreads();
    const short* w = wT + ph * 16384;
    for (int i = threadIdx.x; i < 2048; i += 256) {
      int n = i >> 4, kk = (i & 15) << 3;
      *reinterpret_cast<short8v*>(&wlds[n][kk]) =
          *reinterpret_cast<const short8v*>(w + n * 128 + kk);
    }
    __syncthreads();
    const float* bias = (ph == 0) ? bqs : (ph == 1) ? bk : bv;
    f32x4 zero = {0.f, 0.f, 0.f, 0.f};
    f32x4 acc[8];
    #pragma unroll
    for (int nt = 0; nt < 8; ++nt) acc[nt] = zero;
    #pragma unroll
    for (int nt = 0; nt < 8; ++nt) {
      #pragma unroll
      for (int kk = 0; kk < 4; ++kk) {
        short8v b = *reinterpret_cast<const short8v*>(
            &wlds[nt * 16 + (lane & 15)][kk * 32 + q4 * 8]);
        acc[nt] = mfma16(a[kk], b, acc[nt]);
      }
    }
    short* dst = (ph == 0) ? qout : (ph == 1) ? kout : vtout;
    #pragma unroll
    for (int nt = 0; nt < 8; ++nt) {
      #pragma unroll
      for (int r = 0; r < 4; ++r) {
        int row = row0 + q4 * 4 + r;
        int col = nt * 16 + (lane & 15);
        float v = acc[nt][r] + bias[col];
        if (ph == 2) {
          int b_ = row >> 12, n = row & 4095;
          int np = (n & ~12) | ((n & 4) << 1) | ((n & 8) >> 1);  // sigma perm
          dst[((size_t)b_ * 128 + col) * 4096 + np] = f2bf(v);
        } else {
          dst[(size_t)row * 128 + col] = f2bf(v);
        }
      }
    }
  }
}

// ---------------- flash attention v7: 64 q-rows/wave (2 q-tiles) ------------
// Each K/V LDS fragment read feeds TWO mfma (tile0, tile1) -> MFMA:LDS = 2:1.
// Block = 4 waves x 64 q = 256 q-rows.  2-buf vmcnt(0)+barrier loop (R8),
// conflict-free chunk-major V (R9), sigma-permuted V^T global, no-max softmax.
template <int S>
__global__ __launch_bounds__(256, 2) void attn7_k(
    const short* __restrict__ q, const short* __restrict__ k,
    const short* __restrict__ vt, short* __restrict__ opart,
    float* __restrict__ ls) {
  constexpr int KVLEN = NN / S;
  constexpr int NIT = KVLEN / 32;
  __shared__ short8v smem_v[2048];             // 32 KiB: 2 x (8K K + 8K V)
  char* smem = (char*)smem_v;
  const int tid = threadIdx.x;
  const int lane = tid & 63, warp = tid >> 6;
  const int hh = lane >> 5, ql = lane & 31;
  const int split = (int)blockIdx.x % S;
  const int qb_lin = (int)blockIdx.x / S;
  const int b = qb_lin >> 4, qblk = qb_lin & 15;   // 16 qblks x 256 rows
  const int kv0 = split * KVLEN;

  const size_t bqko = (size_t)b * NN * CC;
  short8v qf0[8], qf1[8];
  {
    int qrow = qblk * 256 + warp * 32 + ql;
    const short* qp = q + bqko + (size_t)qrow * CC + hh * 8;
    #pragma unroll
    for (int dc = 0; dc < 8; ++dc) {
      qf0[dc] = *reinterpret_cast<const short8v*>(qp + dc * 16);
      qf1[dc] = *reinterpret_cast<const short8v*>(qp + 128 * CC + dc * 16);
    }
  }
  const char* kg = (const char*)(k + bqko);
  const char* vg = (const char*)(vt + (size_t)b * CC * NN);

  auto stage = [&](int buf, int it) {
    const int kvo = kv0 + it * 32;
    char* base = smem + buf * 16384;
    #pragma unroll
    for (int p = 0; p < 2; ++p) {
      int c = p * 256 + warp * 64 + lane;
      int krow = c >> 4, kj = c & 15;                 // K: 32 rows x 16 chunks
      gload16(kg + (size_t)(kvo + krow) * 256 + 16 * (kj ^ (krow & 7)),
              base + p * 4096 + warp * 1024);
      // V chunk-major: unit c -> chunk g = c>>7, row d = c&127
      gload16(vg + (size_t)(c & 127) * (NN * 2) + (size_t)kvo * 2 +
                  16 * (c >> 7),
              base + 8192 + p * 4096 + warp * 1024);
    }
  };

  f32x16 oacc0[4] = {Z16, Z16, Z16, Z16};
  f32x16 oacc1[4] = {Z16, Z16, Z16, Z16};
  float l0 = 0.f, l1 = 0.f;

  stage(0, 0);
  asm volatile("s_waitcnt vmcnt(0)" ::: "memory");
  __builtin_amdgcn_s_barrier();

  const int swzK = (ql & 7) << 4;
  for (int it = 0; it < NIT; ++it) {
    const int cur = it & 1;
    if (it + 1 < NIT) stage(cur ^ 1, it + 1);

    // S^T = K x Q for both q-tiles -- each kf read feeds 2 mfma
    const char* kr_p = smem + cur * 16384 + ql * 256;
    f32x16 sT0 = Z16, sT1 = Z16;
    #pragma unroll
    for (int dc = 0; dc < 8; ++dc) {
      short8v kf = *reinterpret_cast<const short8v*>(
          kr_p + ((32 * dc + 16 * hh) ^ swzK));
      sT0 = mfma32(kf, qf0[dc], sT0);
      sT1 = mfma32(kf, qf1[dc], sT1);
    }

    // no-max softmax + pack, tile0 then tile1 (sT dies after its pack)
    unsigned pu0[2][4], pu1[2][4];
    {
      float rs = 0.f;
      #pragma unroll
      for (int r = 0; r < 16; ++r) {
        float p = exp2f(sT0[r]);
        sT0[r] = p; rs += p;
      }
      l0 += rs;
      #pragma unroll
      for (int st = 0; st < 2; ++st)
        #pragma unroll
        for (int w = 0; w < 4; ++w)
          pu0[st][w] = pk2bf(sT0[8 * st + 2 * w], sT0[8 * st + 2 * w + 1]);
    }
    {
      float rs = 0.f;
      #pragma unroll
      for (int r = 0; r < 16; ++r) {
        float p = exp2f(sT1[r]);
        sT1[r] = p; rs += p;
      }
      l1 += rs;
      #pragma unroll
      for (int st = 0; st < 2; ++st)
        #pragma unroll
        for (int w = 0; w < 4; ++w)
          pu1[st][w] = pk2bf(sT1[8 * st + 2 * w], sT1[8 * st + 2 * w + 1]);
    }

    // PV: each vf read feeds 2 mfma (P0, P1)
    const char* vb_ = smem + cur * 16384 + 8192;
    #pragma unroll
    for (int st = 0; st < 2; ++st) {
      union { unsigned u[4]; short8v v; } a0, a1;
      #pragma unroll
      for (int w = 0; w < 4; ++w) { a0.u[w] = pu0[st][w]; a1.u[w] = pu1[st][w]; }
      const char* vr_p = vb_ + (2 * st + hh) * 2048 + ql * 16;
      #pragma unroll
      for (int dt = 0; dt < 4; ++dt) {
        short8v vf = *reinterpret_cast<const short8v*>(vr_p + dt * 512);
        oacc0[dt] = mfma32(a0.v, vf, oacc0[dt]);
        oacc1[dt] = mfma32(a1.v, vf, oacc1[dt]);
      }
    }

    asm volatile("s_waitcnt vmcnt(0)" ::: "memory");
    __builtin_amdgcn_s_barrier();
  }

  // epilogue: cross-half l sums (deferred), normalized bf16 partials + l
  l0 += __shfl_xor(l0, 32);
  l1 += __shfl_xor(l1, 32);
  float ri0 = 1.f / l0, ri1 = 1.f / l1;
  size_t row0 = (size_t)(split * 8 + b) * NN + qblk * 256 + warp * 32;
  short* op = opart + row0 * CC;
  #pragma unroll
  for (int r = 0; r < 16; ++r) {
    int qp = (r & 3) + 8 * (r >> 2) + 4 * hh;
    float ra = __shfl(ri0, qp);
    float rb = __shfl(ri1, qp);
    #pragma unroll
    for (int dt = 0; dt < 4; ++dt) {
      op[(size_t)qp * CC + 32 * dt + ql] = f2bf(oacc0[dt][r] * ra);
      op[(size_t)(qp + 128) * CC + 32 * dt + ql] = f2bf(oacc1[dt][r] * rb);
    }
  }
  if (hh == 0) {
    ls[row0 + ql] = l0;
    ls[row0 + 128 + ql] = l1;
  }
}

// ---------------- fused split-combine + output proj + residual --------------
template <int S>
__global__ __launch_bounds__(256) void projoc_k(const short* __restrict__ opart,
    const float* __restrict__ ls, const short* __restrict__ wT,
    const float* __restrict__ bias, const float* __restrict__ x,
    float* __restrict__ out) {
  __shared__ short wlds[128][136];
  int lane = threadIdx.x & 63, wid = threadIdx.x >> 6;
  for (int i = threadIdx.x; i < 2048; i += 256) {
    int n = i >> 4, kk = (i & 15) << 3;
    *reinterpret_cast<short8v*>(&wlds[n][kk]) =
        *reinterpret_cast<const short8v*>(wT + n * 128 + kk);
  }
  int row0 = blockIdx.x * 64 + wid * 16;
  int arow = row0 + (lane & 15);
  int q4 = lane >> 4;
  float wgt[S];
  {
    float tot = 0.f;
    #pragma unroll
    for (int s = 0; s < S; ++s) {
      wgt[s] = ls[(size_t)s * 32768 + arow];
      tot += wgt[s];
    }
    float inv = 1.f / tot;
    #pragma unroll
    for (int s = 0; s < S; ++s) wgt[s] *= inv;
  }
  short8v a[4];
  #pragma unroll
  for (int dt = 0; dt < 4; ++dt) {
    int c0 = dt * 32 + q4 * 8;
    float acc8[8] = {0.f, 0.f, 0.f, 0.f, 0.f, 0.f, 0.f, 0.f};
    #pragma unroll
    for (int s = 0; s < S; ++s) {
      short8v v = *reinterpret_cast<const short8v*>(
          opart + ((size_t)s * 32768 + arow) * CC + c0);
      #pragma unroll
      for (int e = 0; e < 8; ++e) acc8[e] += wgt[s] * bf2f(v[e]);
    }
    union { short s[8]; short8v v; } pk;
    #pragma unroll
    for (int e = 0; e < 8; ++e) pk.s[e] = f2bf(acc8[e]);
    a[dt] = pk.v;
  }
  __syncthreads();
  f32x4 zero = {0.f, 0.f, 0.f, 0.f};
  f32x4 acc[8];
  #pragma unroll
  for (int nt = 0; nt < 8; ++nt) acc[nt] = zero;
  #pragma unroll
  for (int nt = 0; nt < 8; ++nt) {
    #pragma unroll
    for (int kk = 0; kk < 4; ++kk) {
      short8v b = *reinterpret_cast<const short8v*>(
          &wlds[nt * 16 + (lane & 15)][kk * 32 + q4 * 8]);
      acc[nt] = mfma16(a[kk], b, acc[nt]);
    }
  }
  #pragma unroll
  for (int nt = 0; nt < 8; ++nt) {
    #pragma unroll
    for (int r = 0; r < 4; ++r) {
      int row = row0 + q4 * 4 + r;
      int col = nt * 16 + (lane & 15);
      out[(size_t)row * 128 + col] =
          acc[nt][r] + bias[col] + x[(size_t)row * 128 + col];
    }
  }
}

// ---------------- launch -----------------------------------------------------
extern "C" void kernel_launch(void* const* d_in, const int* in_sizes, int n_in,
                              void* d_out, int out_size, void* d_ws, size_t ws_size,
                              hipStream_t stream) {
  (void)in_sizes; (void)n_in; (void)out_size;
  const float* x   = (const float*)d_in[0];
  const float* gsc = (const float*)d_in[1];
  const float* gbi = (const float*)d_in[2];
  const float* wq  = (const float*)d_in[3];
  const float* bq  = (const float*)d_in[4];
  const float* wk  = (const float*)d_in[5];
  const float* bk  = (const float*)d_in[6];
  const float* wv  = (const float*)d_in[7];
  const float* bv  = (const float*)d_in[8];
  const float* wo  = (const float*)d_in[9];
  const float* bo  = (const float*)d_in[10];
  float* out = (float*)d_out;

  char* ws = (char*)d_ws;
  constexpr size_t OFF_WT   = 0;                        // 131072
  constexpr size_t OFF_BQS  = 131072;                   // 512
  constexpr size_t OFF_MACC = 131584;                   // 1024
  constexpr size_t OFF_VACC = 132608;                   // 1024
  constexpr size_t OFF_QB   = 133632;                   // 8 MiB
  constexpr size_t OFF_KB   = OFF_QB + 8388608;
  constexpr size_t OFF_VT   = OFF_KB + 8388608;
  constexpr size_t OFF_OP   = OFF_VT + 8388608;         // S * 8 MiB + S*128K ls
  constexpr size_t NEED4 = OFF_OP + 4 * 8388608 + 4 * 131072;
  constexpr size_t NEED2 = OFF_OP + 2 * 8388608 + 2 * 131072;

  short* wT   = (short*)(ws + OFF_WT);
  float* bqs  = (float*)(ws + OFF_BQS);
  float* macc = (float*)(ws + OFF_MACC);
  float* vacc = (float*)(ws + OFF_VACC);
  short* qb   = (short*)(ws + OFF_QB);
  short* kb   = (short*)(ws + OFF_KB);
  short* vtb  = (short*)(ws + OFF_VT);
  short* opart= (short*)(ws + OFF_OP);
  const int S = (ws_size >= NEED4) ? 4 : (ws_size >= NEED2) ? 2 : 1;
  float* ls = (float*)(ws + OFF_OP + (size_t)S * 8388608);

  hipMemsetAsync(ws + OFF_MACC, 0, 2048, stream);       // zero macc+vacc
  prep_k<<<512, 256, 0, stream>>>(x, wq, wk, wv, wo, bq, wT, bqs, macc, vacc);
  fqkv_k<<<512, 256, 0, stream>>>(x, macc, vacc, gsc, gbi, wT, bqs, bk, bv,
                                  qb, kb, vtb);
  if (S == 4) {
    attn7_k<4><<<512, 256, 0, stream>>>(qb, kb, vtb, opart, ls);
    projoc_k<4><<<512, 256, 0, stream>>>(opart, ls, wT + 49152, bo, x, out);
  } else if (S == 2) {
    attn7_k<2><<<256, 256, 0, stream>>>(qb, kb, vtb, opart, ls);
    projoc_k<2><<<512, 256, 0, stream>>>(opart, ls, wT + 49152, bo, x, out);
  } else {
    attn7_k<1><<<128, 256, 0, stream>>>(qb, kb, vtb, opart, ls);
    projoc_k<1><<<512, 256, 0, stream>>>(opart, ls, wT + 49152, bo, x, out);
  }
}

// Round 12
// 126.775 us; speedup vs baseline: 1.0421x; 1.0421x over previous
//
#include <hip/hip_runtime.h>
#include <hip/hip_bf16.h>

#define NN 4096
#define CC 128
#define SCALE 0.088388347648318447f   // 128^-0.5
#define LOG2E 1.4426950408889634f

typedef __attribute__((ext_vector_type(8))) short short8v;
typedef __attribute__((ext_vector_type(4))) float f32x4;
typedef __attribute__((ext_vector_type(16))) float f32x16;

#define Z16 {0.f,0.f,0.f,0.f,0.f,0.f,0.f,0.f,0.f,0.f,0.f,0.f,0.f,0.f,0.f,0.f}

__device__ __forceinline__ short f2bf(float f) {
  unsigned u = __float_as_uint(f);
  u = (u + 0x7FFFu + ((u >> 16) & 1u)) >> 16;
  return (short)u;
}
__device__ __forceinline__ float bf2f(short s) {
  return __uint_as_float(((unsigned)(unsigned short)s) << 16);
}
__device__ __forceinline__ unsigned pk2bf(float lo, float hi) {
  unsigned r;
  asm("v_cvt_pk_bf16_f32 %0, %1, %2" : "=v"(r) : "v"(lo), "v"(hi));
  return r;
}
__device__ __forceinline__ f32x4 mfma16(short8v a, short8v b, f32x4 c) {
  return __builtin_amdgcn_mfma_f32_16x16x32_bf16(a, b, c, 0, 0, 0);
}
__device__ __forceinline__ f32x16 mfma32(short8v a, short8v b, f32x16 c) {
  return __builtin_amdgcn_mfma_f32_32x32x16_bf16(a, b, c, 0, 0, 0);
}
__device__ __forceinline__ void gload16(const void* g, void* l) {
  __builtin_amdgcn_global_load_lds(
      (const __attribute__((address_space(1))) unsigned*)g,
      (__attribute__((address_space(3))) unsigned*)l, 16, 0, 0);
}

// ---------------- prep: weight convert + groupnorm partial sums -------------
__global__ __launch_bounds__(256) void prep_k(
    const float* __restrict__ x,
    const float* __restrict__ wq, const float* __restrict__ wk,
    const float* __restrict__ wv, const float* __restrict__ wo,
    const float* __restrict__ bq, short* __restrict__ wT,
    float* __restrict__ bqs, float* __restrict__ macc,
    float* __restrict__ vacc) {
  if (blockIdx.x >= 256) {
    int gid = (blockIdx.x - 256) * 256 + threadIdx.x;   // 4*16384
    int widx = gid >> 14, e = gid & 16383;
    int kk = e >> 7, n = e & 127;
    const float* src = (widx == 0) ? wq : (widx == 1) ? wk
                     : (widx == 2) ? wv : wo;
    float v = src[kk * 128 + n];
    if (widx == 0) v *= SCALE * LOG2E;
    wT[widx * 16384 + n * 128 + kk] = f2bf(v);
    if (gid < 128) bqs[gid] = bq[gid] * SCALE * LOG2E;
    return;
  }
  // GN partial: batch b, rows [rc*128, rc*128+128) -- contiguous 64 KB
  int b = blockIdx.x >> 5, rc = blockIdx.x & 31;
  const float4* xp = reinterpret_cast<const float4*>(
      x + (size_t)b * NN * CC + (size_t)rc * 128 * CC);
  int tid = threadIdx.x;
  float s = 0.f, ss = 0.f;
  #pragma unroll
  for (int j = 0; j < 16; ++j) {               // float4 idx = tid + 256j
    float4 v = xp[tid + 256 * j];              // group = idx&31 = tid&31
    s  += v.x + v.y + v.z + v.w;
    ss += v.x * v.x + v.y * v.y + v.z * v.z + v.w * v.w;
  }
  __shared__ float as_[256], ass_[256];
  as_[tid] = s; ass_[tid] = ss;
  __syncthreads();
  if (tid < 32) {                              // 8 threads per group -> sum
    float ts = 0.f, tss = 0.f;
    #pragma unroll
    for (int j = 0; j < 8; ++j) { ts += as_[tid + 32 * j]; tss += ass_[tid + 32 * j]; }
    atomicAdd(&macc[b * 32 + tid], ts);
    atomicAdd(&vacc[b * 32 + tid], tss);
  }
}

// ---------------- fused GN-apply + Q/K/V projections ------------------------
__global__ __launch_bounds__(256) void fqkv_k(
    const float* __restrict__ x, const float* __restrict__ macc,
    const float* __restrict__ vacc, const float* __restrict__ gsc,
    const float* __restrict__ gbi, const short* __restrict__ wT,
    const float* __restrict__ bqs, const float* __restrict__ bk,
    const float* __restrict__ bv, short* __restrict__ qout,
    short* __restrict__ kout, short* __restrict__ vtout) {
  __shared__ short wlds[128][136];
  int lane = threadIdx.x & 63, wid = threadIdx.x >> 6;
  int row0 = blockIdx.x * 64 + wid * 16;
  int arow = row0 + (lane & 15);
  int q4 = lane >> 4;
  int bidx = arow >> 12;
  short8v a[4];
  #pragma unroll
  for (int dt = 0; dt < 4; ++dt) {
    int c0 = dt * 32 + q4 * 8;
    float4 v0 = *reinterpret_cast<const float4*>(x + (size_t)arow * CC + c0);
    float4 v1 = *reinterpret_cast<const float4*>(x + (size_t)arow * CC + c0 + 4);
    int g0 = bidx * 32 + (c0 >> 2);
    float mu0 = macc[g0] * (1.f / 16384.f);
    float r0 = rsqrtf(vacc[g0] * (1.f / 16384.f) - mu0 * mu0 + 1e-6f);
    float mu1 = macc[g0 + 1] * (1.f / 16384.f);
    float r1 = rsqrtf(vacc[g0 + 1] * (1.f / 16384.f) - mu1 * mu1 + 1e-6f);
    float4 s0 = *reinterpret_cast<const float4*>(gsc + c0);
    float4 s1 = *reinterpret_cast<const float4*>(gsc + c0 + 4);
    float4 b0 = *reinterpret_cast<const float4*>(gbi + c0);
    float4 b1 = *reinterpret_cast<const float4*>(gbi + c0 + 4);
    union { short s[8]; short8v v; } pk;
    pk.s[0] = f2bf((v0.x - mu0) * r0 * s0.x + b0.x);
    pk.s[1] = f2bf((v0.y - mu0) * r0 * s0.y + b0.y);
    pk.s[2] = f2bf((v0.z - mu0) * r0 * s0.z + b0.z);
    pk.s[3] = f2bf((v0.w - mu0) * r0 * s0.w + b0.w);
    pk.s[4] = f2bf((v1.x - mu1) * r1 * s1.x + b1.x);
    pk.s[5] = f2bf((v1.y - mu1) * r1 * s1.y + b1.y);
    pk.s[6] = f2bf((v1.z - mu1) * r1 * s1.z + b1.z);
    pk.s[7] = f2bf((v1.w - mu1) * r1 * s1.w + b1.w);
    a[dt] = pk.v;
  }
  for (int ph = 0; ph < 3; ++ph) {
    if (ph) __syncthreads();
    const short* w = wT + ph * 16384;
    for (int i = threadIdx.x; i < 2048; i += 256) {
      int n = i >> 4, kk = (i & 15) << 3;
      *reinterpret_cast<short8v*>(&wlds[n][kk]) =
          *reinterpret_cast<const short8v*>(w + n * 128 + kk);
    }
    __syncthreads();
    const float* bias = (ph == 0) ? bqs : (ph == 1) ? bk : bv;
    f32x4 zero = {0.f, 0.f, 0.f, 0.f};
    f32x4 acc[8];
    #pragma unroll
    for (int nt = 0; nt < 8; ++nt) acc[nt] = zero;
    #pragma unroll
    for (int nt = 0; nt < 8; ++nt) {
      #pragma unroll
      for (int kk = 0; kk < 4; ++kk) {
        short8v b = *reinterpret_cast<const short8v*>(
            &wlds[nt * 16 + (lane & 15)][kk * 32 + q4 * 8]);
        acc[nt] = mfma16(a[kk], b, acc[nt]);
      }
    }
    short* dst = (ph == 0) ? qout : (ph == 1) ? kout : vtout;
    #pragma unroll
    for (int nt = 0; nt < 8; ++nt) {
      #pragma unroll
      for (int r = 0; r < 4; ++r) {
        int row = row0 + q4 * 4 + r;
        int col = nt * 16 + (lane & 15);
        float v = acc[nt][r] + bias[col];
        if (ph == 2) {
          int b_ = row >> 12, n = row & 4095;
          dst[((size_t)b_ * 128 + col) * 4096 + n] = f2bf(v);
        } else {
          dst[(size_t)row * 128 + col] = f2bf(v);
        }
      }
    }
  }
}

// ---------------- flash attention v5: zero cross-lane ops in loop -----------
// (R8-proven kernel, byte-identical.)  2-buf, vmcnt(0)+barrier; PV A-frag =
// cvt_pk(sT) direct (pi absorbed by b64-pair V reads); deferred l sum.
template <int S>
__global__ __launch_bounds__(256, 3) void attn5_k(
    const short* __restrict__ q, const short* __restrict__ k,
    const short* __restrict__ vt, short* __restrict__ opart,
    float* __restrict__ ls) {
  constexpr int KVLEN = NN / S;
  constexpr int NIT = KVLEN / 32;
  __shared__ short8v smem_v[2048];             // 32 KiB: 2 x (8K K + 8K V)
  char* smem = (char*)smem_v;
  const int tid = threadIdx.x;
  const int lane = tid & 63, warp = tid >> 6;
  const int hh = lane >> 5, ql = lane & 31;
  const int split = (int)blockIdx.x % S;
  const int qb_lin = (int)blockIdx.x / S;
  const int b = qb_lin >> 5, qblk = qb_lin & 31;
  const int kv0 = split * KVLEN;

  const size_t bqko = (size_t)b * NN * CC;
  short8v qf[8];
  {
    int qrow = qblk * 128 + warp * 32 + ql;
    const short* qp = q + bqko + (size_t)qrow * CC + hh * 8;
    #pragma unroll
    for (int dc = 0; dc < 8; ++dc)
      qf[dc] = *reinterpret_cast<const short8v*>(qp + dc * 16);
  }
  const char* kg = (const char*)(k + bqko);
  const char* vg = (const char*)(vt + (size_t)b * CC * NN);

  auto stage = [&](int buf, int it) {
    const int kvo = kv0 + it * 32;
    char* base = smem + buf * 16384;
    #pragma unroll
    for (int p = 0; p < 2; ++p) {
      int c = p * 256 + warp * 64 + lane;
      int krow = c >> 4, kj = c & 15;                 // K: 32 rows x 16 chunks
      gload16(kg + (size_t)(kvo + krow) * 256 + 16 * (kj ^ (krow & 7)),
              base + p * 4096 + warp * 1024);
      int vd = c >> 2, vj = c & 3;                    // V: 128 rows x 4 chunks
      gload16(vg + (size_t)vd * (NN * 2) + (size_t)kvo * 2 +
                  16 * (vj ^ ((vd >> 1) & 3)),
              base + 8192 + p * 4096 + warp * 1024);
    }
  };

  f32x16 oacc[4] = {Z16, Z16, Z16, Z16};
  float l_run = 0.f;

  stage(0, 0);
  asm volatile("s_waitcnt vmcnt(0)" ::: "memory");
  __builtin_amdgcn_s_barrier();

  const int swzK = (ql & 7) << 4;
  const int swzV = (ql & 6) << 3;                     // 16*((ql>>1)&3)
  for (int it = 0; it < NIT; ++it) {
    const int cur = it & 1;
    if (it + 1 < NIT) stage(cur ^ 1, it + 1);

    // S^T = K x Q  (32k x 32q per wave)
    const char* kr_p = smem + cur * 16384 + ql * 256;
    f32x16 sT = Z16;
    #pragma unroll
    for (int dc = 0; dc < 8; ++dc) {
      short8v kf = *reinterpret_cast<const short8v*>(
          kr_p + ((32 * dc + 16 * hh) ^ swzK));
      sT = mfma32(kf, qf[dc], sT);
    }

    // softmax without max-subtraction: p = exp2(s); own-half partial sum only
    float rsum = 0.f;
    #pragma unroll
    for (int r = 0; r < 16; ++r) {
      float p = exp2f(sT[r]);
      sT[r] = p; rsum += p;
    }
    l_run += rsum;

    // PV: A-frag = cvt_pk(sT) direct; V read as two b64 halves (pi-permuted)
    const char* vb_ = smem + cur * 16384 + 8192;
    #pragma unroll
    for (int st = 0; st < 2; ++st) {
      union { unsigned u[4]; short8v v; } pu;
      #pragma unroll
      for (int w = 0; w < 4; ++w)
        pu.u[w] = pk2bf(sT[8 * st + 2 * w], sT[8 * st + 2 * w + 1]);
      const int o1 = (32 * st + 8 * hh) ^ swzV;
      const int o2 = (32 * st + 8 * hh + 16) ^ swzV;
      #pragma unroll
      for (int dt = 0; dt < 4; ++dt) {
        const char* vr_p = vb_ + (32 * dt + ql) * 64;
        union { unsigned long long d[2]; short8v v; } vf;
        vf.d[0] = *reinterpret_cast<const unsigned long long*>(vr_p + o1);
        vf.d[1] = *reinterpret_cast<const unsigned long long*>(vr_p + o2);
        oacc[dt] = mfma32(pu.v, vf.v, oacc[dt]);
      }
    }

    asm volatile("s_waitcnt vmcnt(0)" ::: "memory");
    __builtin_amdgcn_s_barrier();
  }

  // epilogue: cross-half l sum (deferred), normalized bf16 partial + l
  l_run += __shfl_xor(l_run, 32);
  float rinv = 1.f / l_run;
  short* op = opart + ((size_t)(split * 8 + b) * NN + qblk * 128 + warp * 32) * CC;
  #pragma unroll
  for (int r = 0; r < 16; ++r) {
    int qp = (r & 3) + 8 * (r >> 2) + 4 * hh;
    float ri = __shfl(rinv, qp);
    #pragma unroll
    for (int dt = 0; dt < 4; ++dt)
      op[(size_t)qp * CC + 32 * dt + ql] = f2bf(oacc[dt][r] * ri);
  }
  if (hh == 0) {
    size_t ix = (size_t)(split * 8 + b) * NN + qblk * 128 + warp * 32 + ql;
    ls[ix] = l_run;
  }
}

// ---------------- fused split-combine + output proj + residual --------------
template <int S>
__global__ __launch_bounds__(256) void projoc_k(const short* __restrict__ opart,
    const float* __restrict__ ls, const short* __restrict__ wT,
    const float* __restrict__ bias, const float* __restrict__ x,
    float* __restrict__ out) {
  __shared__ short wlds[128][136];
  int lane = threadIdx.x & 63, wid = threadIdx.x >> 6;
  for (int i = threadIdx.x; i < 2048; i += 256) {
    int n = i >> 4, kk = (i & 15) << 3;
    *reinterpret_cast<short8v*>(&wlds[n][kk]) =
        *reinterpret_cast<const short8v*>(wT + n * 128 + kk);
  }
  int row0 = blockIdx.x * 64 + wid * 16;
  int arow = row0 + (lane & 15);
  int q4 = lane >> 4;
  float wgt[S];
  {
    float tot = 0.f;
    #pragma unroll
    for (int s = 0; s < S; ++s) {
      wgt[s] = ls[(size_t)s * 32768 + arow];
      tot += wgt[s];
    }
    float inv = 1.f / tot;
    #pragma unroll
    for (int s = 0; s < S; ++s) wgt[s] *= inv;
  }
  short8v a[4];
  #pragma unroll
  for (int dt = 0; dt < 4; ++dt) {
    int c0 = dt * 32 + q4 * 8;
    float acc8[8] = {0.f, 0.f, 0.f, 0.f, 0.f, 0.f, 0.f, 0.f};
    #pragma unroll
    for (int s = 0; s < S; ++s) {
      short8v v = *reinterpret_cast<const short8v*>(
          opart + ((size_t)s * 32768 + arow) * CC + c0);
      #pragma unroll
      for (int e = 0; e < 8; ++e) acc8[e] += wgt[s] * bf2f(v[e]);
    }
    union { short s[8]; short8v v; } pk;
    #pragma unroll
    for (int e = 0; e < 8; ++e) pk.s[e] = f2bf(acc8[e]);
    a[dt] = pk.v;
  }
  __syncthreads();
  f32x4 zero = {0.f, 0.f, 0.f, 0.f};
  f32x4 acc[8];
  #pragma unroll
  for (int nt = 0; nt < 8; ++nt) acc[nt] = zero;
  #pragma unroll
  for (int nt = 0; nt < 8; ++nt) {
    #pragma unroll
    for (int kk = 0; kk < 4; ++kk) {
      short8v b = *reinterpret_cast<const short8v*>(
          &wlds[nt * 16 + (lane & 15)][kk * 32 + q4 * 8]);
      acc[nt] = mfma16(a[kk], b, acc[nt]);
    }
  }
  #pragma unroll
  for (int nt = 0; nt < 8; ++nt) {
    #pragma unroll
    for (int r = 0; r < 4; ++r) {
      int row = row0 + q4 * 4 + r;
      int col = nt * 16 + (lane & 15);
      out[(size_t)row * 128 + col] =
          acc[nt][r] + bias[col] + x[(size_t)row * 128 + col];
    }
  }
}

// ---------------- launch -----------------------------------------------------
extern "C" void kernel_launch(void* const* d_in, const int* in_sizes, int n_in,
                              void* d_out, int out_size, void* d_ws, size_t ws_size,
                              hipStream_t stream) {
  (void)in_sizes; (void)n_in; (void)out_size;
  const float* x   = (const float*)d_in[0];
  const float* gsc = (const float*)d_in[1];
  const float* gbi = (const float*)d_in[2];
  const float* wq  = (const float*)d_in[3];
  const float* bq  = (const float*)d_in[4];
  const float* wk  = (const float*)d_in[5];
  const float* bk  = (const float*)d_in[6];
  const float* wv  = (const float*)d_in[7];
  const float* bv  = (const float*)d_in[8];
  const float* wo  = (const float*)d_in[9];
  const float* bo  = (const float*)d_in[10];
  float* out = (float*)d_out;

  char* ws = (char*)d_ws;
  constexpr size_t OFF_WT   = 0;                        // 131072
  constexpr size_t OFF_BQS  = 131072;                   // 512
  constexpr size_t OFF_MACC = 131584;                   // 1024
  constexpr size_t OFF_VACC = 132608;                   // 1024
  constexpr size_t OFF_QB   = 133632;                   // 8 MiB
  constexpr size_t OFF_KB   = OFF_QB + 8388608;
  constexpr size_t OFF_VT   = OFF_KB + 8388608;
  constexpr size_t OFF_OP   = OFF_VT + 8388608;         // S * 8 MiB + S*128K ls
  constexpr size_t NEED2 = OFF_OP + 2 * 8388608 + 2 * 131072;

  short* wT   = (short*)(ws + OFF_WT);
  float* bqs  = (float*)(ws + OFF_BQS);
  float* macc = (float*)(ws + OFF_MACC);
  float* vacc = (float*)(ws + OFF_VACC);
  short* qb   = (short*)(ws + OFF_QB);
  short* kb   = (short*)(ws + OFF_KB);
  short* vtb  = (short*)(ws + OFF_VT);
  short* opart= (short*)(ws + OFF_OP);
  const int S = (ws_size >= NEED2) ? 2 : 1;
  float* ls = (float*)(ws + OFF_OP + (size_t)S * 8388608);

  hipMemsetAsync(ws + OFF_MACC, 0, 2048, stream);       // zero macc+vacc
  prep_k<<<512, 256, 0, stream>>>(x, wq, wk, wv, wo, bq, wT, bqs, macc, vacc);
  fqkv_k<<<512, 256, 0, stream>>>(x, macc, vacc, gsc, gbi, wT, bqs, bk, bv,
                                  qb, kb, vtb);
  if (S == 2) {
    attn5_k<2><<<512, 256, 0, stream>>>(qb, kb, vtb, opart, ls);
    projoc_k<2><<<512, 256, 0, stream>>>(opart, ls, wT + 49152, bo, x, out);
  } else {
    attn5_k<1><<<256, 256, 0, stream>>>(qb, kb, vtb, opart, ls);
    projoc_k<1><<<512, 256, 0, stream>>>(opart, ls, wT + 49152, bo, x, out);
  }
}